// Round 9
// baseline (488.919 us; speedup 1.0000x reference)
//
#include <hip/hip_runtime.h>
#include <cstdint>
#include <cstddef>

#define NN 100000
#define NP 100096          // rows padded to multiple of 64
#define EE 1600000
#define ET 1700000         // EE + NN self-loops
#define NBKT 196           // ceil(NN/512) dst-range buckets
#define TILE 2048          // edges per k_bucket block
#define STAT_BLOCKS 400

typedef short  bf16x8 __attribute__((ext_vector_type(8)));
typedef float  f32x4  __attribute__((ext_vector_type(4)));

__device__ __forceinline__ unsigned short f2bf(float f) {
    unsigned int x = __builtin_bit_cast(unsigned int, f);
    x += 0x7FFFu + ((x >> 16) & 1u);   // RNE
    return (unsigned short)(x >> 16);
}
__device__ __forceinline__ unsigned int pk2(float lo, float hi) {
    return ((unsigned int)f2bf(hi) << 16) | (unsigned int)f2bf(lo);
}
__device__ __forceinline__ float bflo(unsigned int u) {
    return __builtin_bit_cast(float, u << 16);
}
__device__ __forceinline__ float bfhi(unsigned int u) {
    return __builtin_bit_cast(float, u & 0xFFFF0000u);
}
// permuted H layout: stored pos j <-> orig col ((j&7)<<4)|(j>>3)  (j = c*8+nt, col = nt*16+c)
__device__ __forceinline__ int unperm(int j) { return ((j & 7) << 4) | (j >> 3); }

// ======================= fused bcount + weight cvt (independent work, one launch) ==========
// blocks 0..255: dst-bucket histogram.  blocks 256..447: weight conversion into
// FRAGMENT-MAJOR layout WbT[(nt*4+k0)*64 + lane] so k_mfma's B-loads are lane-coalesced
// (r7 post-mortem: row-major B-fragments scattered 64 lanes over 32 cache lines/instr;
// r8 confirmed big mfma win).
__global__ void k_pre(const int* __restrict__ ei,
                      const float* __restrict__ W0, const float* __restrict__ W1,
                      const float* __restrict__ W2, unsigned short* __restrict__ Wb,
                      int* __restrict__ btot)
{
    const int t = threadIdx.x;
    const int b = blockIdx.x;
    if (b < 256) {
        __shared__ int h[256];
        h[t] = 0;
        __syncthreads();
        for (int e = b * 256 + t; e < ET; e += 256 * 256) {
            int d = (e < EE) ? ei[EE + e] : (e - EE);
            atomicAdd(&h[d >> 9], 1);
        }
        __syncthreads();
        if (h[t]) atomicAdd(&btot[t], h[t]);
    } else {
        int i = (b - 256) * 256 + t;       // 0..49151
        int layer = i >> 14;
        const float* W = (layer == 0) ? W0 : (layer == 1) ? W1 : W2;
        int o  = i & 16383;
        int f  = o >> 3, e = o & 7;
        int nt = f >> 8, k0 = (f >> 6) & 3, lane = f & 63;
        int c  = lane & 15, q = lane >> 4;
        int k  = k0 * 32 + q * 8 + e;          // logical k index of A-fragment elem
        int col = (layer == 0) ? k : unperm(k); // layers 1/2 consume permuted H
        Wb[i] = f2bf(W[(nt * 16 + c) * 128 + col]);
    }
}

__global__ void k_bscan(const int* __restrict__ btot, int* __restrict__ bstart,
                        int* __restrict__ bcur, int* __restrict__ off) {
    __shared__ int s[256];
    int t = threadIdx.x;
    int v = (t < NBKT) ? btot[t] : 0;
    s[t] = v;
    __syncthreads();
    for (int o = 1; o < 256; o <<= 1) {
        int a = (t >= o) ? s[t - o] : 0;
        __syncthreads();
        s[t] += a;
        __syncthreads();
    }
    int ex = s[t] - v;
    if (t <= NBKT) bstart[t] = (t < NBKT) ? ex : ET;
    if (t == NBKT - 1) bstart[NBKT] = s[t];   // == ET
    bcur[t] = ex;
    if (t == 0) off[NN] = ET;
}

__global__ __launch_bounds__(256) void k_bucket(
    const int* __restrict__ ei, int* __restrict__ bcur, unsigned int* __restrict__ bucketed)
{
    __shared__ int h4[4][256], woff[4][256], loff[256], gbase[256], sc[256];
    __shared__ unsigned int stage[TILE];
    __shared__ int gaddr[TILE];
    __shared__ int stot_s;
    const int t = threadIdx.x;
    const int w = t >> 6;
    const int e0 = blockIdx.x * TILE;

    h4[0][t] = 0; h4[1][t] = 0; h4[2][t] = 0; h4[3][t] = 0;
    __syncthreads();

    unsigned int pk[TILE / 256];
    int bk[TILE / 256];
#pragma unroll
    for (int i = 0; i < TILE / 256; ++i) {
        int e = e0 + i * 256 + t;
        bk[i] = -1;
        if (e < ET) {
            int s, d;
            if (e < EE) { s = ei[e]; d = ei[EE + e]; } else { s = e - EE; d = s; }
            bk[i] = d >> 9;
            pk[i] = ((unsigned int)(d & 511) << 17) | (unsigned int)s;
            atomicAdd(&h4[w][bk[i]], 1);
        }
    }
    __syncthreads();

    int h0 = h4[0][t], h1 = h4[1][t], h2 = h4[2][t], h3 = h4[3][t];
    int tot = h0 + h1 + h2 + h3;
    sc[t] = tot;
    __syncthreads();
    for (int o = 1; o < 256; o <<= 1) {
        int a = (t >= o) ? sc[t - o] : 0;
        __syncthreads();
        sc[t] += a;
        __syncthreads();
    }
    int lo = sc[t] - tot;
    loff[t] = lo;
    woff[0][t] = lo;
    woff[1][t] = lo + h0;
    woff[2][t] = lo + h0 + h1;
    woff[3][t] = lo + h0 + h1 + h2;
    if (t < NBKT && tot) gbase[t] = atomicAdd(&bcur[t], tot);
    if (t == 255) stot_s = sc[255];
    h4[0][t] = 0; h4[1][t] = 0; h4[2][t] = 0; h4[3][t] = 0;
    __syncthreads();

#pragma unroll
    for (int i = 0; i < TILE / 256; ++i) {
        if (bk[i] >= 0) {
            int b = bk[i];
            int r = woff[w][b] + atomicAdd(&h4[w][b], 1);
            stage[r] = pk[i];
            gaddr[r] = gbase[b] + (r - loff[b]);
        }
    }
    __syncthreads();

    const int stot = stot_s;
    for (int j = t; j < stot; j += 256)
        bucketed[gaddr[j]] = stage[j];
}

__global__ __launch_bounds__(256) void k_csr(
    const unsigned int* __restrict__ bucketed, const int* __restrict__ bstart,
    int* __restrict__ off, int* __restrict__ srcs)
{
    __shared__ int h[512], sc2[512], c2[512], sp[256];
    const int t = threadIdx.x;
    const int b = blockIdx.x;
    const int beg = bstart[b], end = bstart[b + 1];
    const int cnt = end - beg;

    h[t] = 0; h[t + 256] = 0; c2[t] = 0; c2[t + 256] = 0;
    __syncthreads();
    for (int i = t; i < cnt; i += 256)
        atomicAdd(&h[bucketed[beg + i] >> 17], 1);
    __syncthreads();

    int a0 = h[2 * t], a1 = h[2 * t + 1];
    sp[t] = a0 + a1;
    __syncthreads();
    for (int o = 1; o < 256; o <<= 1) {
        int a = (t >= o) ? sp[t - o] : 0;
        __syncthreads();
        sp[t] += a;
        __syncthreads();
    }
    int ep = sp[t] - (a0 + a1);
    sc2[2 * t] = ep;
    sc2[2 * t + 1] = ep + a0;
    __syncthreads();

    const int d0 = b << 9;
#pragma unroll
    for (int k = t; k < 512; k += 256) {
        int d = d0 + k;
        if (d < NN) off[d] = beg + sc2[k];
    }

    for (int i = t; i < cnt; i += 256) {
        unsigned int v = bucketed[beg + i];
        int ld = v >> 17;
        int r = atomicAdd(&c2[ld], 1);
        srcs[beg + sc2[ld] + r] = (int)(v & 0x1FFFFu);
    }
}

// ======================= MFMA GEMM: H = X @ W^T, fused BN-affine/relu/cvt + AS/AD ===========
// MODE 0: fp32 X read (layer 0); MODE 1: permuted-bf16 X read + BN affine + relu.
// B-fragments from fragment-major WbT (lane-coalesced). Direct permuted Hb store (r6).
template<int MODE>
__global__ __launch_bounds__(256) void k_mfma(
    const void* __restrict__ Xv, const unsigned short* __restrict__ Wb,
    const float* __restrict__ gsum, const float* __restrict__ gsq,
    const float* __restrict__ gamma, const float* __restrict__ beta,
    const float* __restrict__ asrc, const float* __restrict__ adst,
    unsigned short* __restrict__ Hb, float* __restrict__ AS, float* __restrict__ AD)
{
    __shared__ float scale_s[128], shift_s[128];
    const int t    = threadIdx.x;
    const int lane = t & 63;
    const int c    = lane & 15;
    const int q    = lane >> 4;
    const int r0   = blockIdx.x * 64 + (t >> 6) * 16;
    const int row  = r0 + c;

    if (MODE) {
        // BN affine from raw sums; stats arrive in PERMUTED/stored col order
        if (t < 128) {
            int ot = unperm(t);
            float mu  = gsum[t] * (1.f / NN);
            float var = gsq[t] * (1.f / NN) - mu * mu;
            float sc  = gamma[ot] * rsqrtf(var + 1e-5f);
            scale_s[t] = sc;
            shift_s[t] = beta[ot] - mu * sc;
        }
        __syncthreads();
    }

    union { uint4 u; bf16x8 v; } Af[4];
    if (row < NN) {
        if (MODE) {
            const unsigned short* xp = (const unsigned short*)Xv + ((size_t)row << 7) + (q << 3);
#pragma unroll
            for (int k0 = 0; k0 < 4; ++k0) {
                uint4 r = *(const uint4*)(xp + (k0 << 5));
                const int kb = (k0 << 5) + (q << 3);
                float a0 = bflo(r.x), a1 = bfhi(r.x), a2 = bflo(r.y), a3 = bfhi(r.y);
                float a4 = bflo(r.z), a5 = bfhi(r.z), a6 = bflo(r.w), a7 = bfhi(r.w);
                float4 sA = *(const float4*)&scale_s[kb];
                float4 sB = *(const float4*)&scale_s[kb + 4];
                float4 hA = *(const float4*)&shift_s[kb];
                float4 hB = *(const float4*)&shift_s[kb + 4];
                a0 = fmaxf(0.f, fmaf(a0, sA.x, hA.x));
                a1 = fmaxf(0.f, fmaf(a1, sA.y, hA.y));
                a2 = fmaxf(0.f, fmaf(a2, sA.z, hA.z));
                a3 = fmaxf(0.f, fmaf(a3, sA.w, hA.w));
                a4 = fmaxf(0.f, fmaf(a4, sB.x, hB.x));
                a5 = fmaxf(0.f, fmaf(a5, sB.y, hB.y));
                a6 = fmaxf(0.f, fmaf(a6, sB.z, hB.z));
                a7 = fmaxf(0.f, fmaf(a7, sB.w, hB.w));
                Af[k0].u.x = pk2(a0, a1);
                Af[k0].u.y = pk2(a2, a3);
                Af[k0].u.z = pk2(a4, a5);
                Af[k0].u.w = pk2(a6, a7);
            }
        } else {
            const float* xp = (const float*)Xv + ((size_t)row << 7) + (q << 3);
#pragma unroll
            for (int k0 = 0; k0 < 4; ++k0) {
                float4 a = *(const float4*)(xp + (k0 << 5));
                float4 b = *(const float4*)(xp + (k0 << 5) + 4);
                Af[k0].u.x = pk2(a.x, a.y);
                Af[k0].u.y = pk2(a.z, a.w);
                Af[k0].u.z = pk2(b.x, b.y);
                Af[k0].u.w = pk2(b.z, b.w);
            }
        }
    } else {
#pragma unroll
        for (int k0 = 0; k0 < 4; ++k0) Af[k0].u = make_uint4(0, 0, 0, 0);
    }

    f32x4 acc[8];
#pragma unroll
    for (int nt = 0; nt < 8; ++nt) acc[nt] = (f32x4){0.f, 0.f, 0.f, 0.f};

#pragma unroll
    for (int nt = 0; nt < 8; ++nt) {
        union { uint4 u; bf16x8 v; } Bf[4];
#pragma unroll
        for (int k0 = 0; k0 < 4; ++k0)
            Bf[k0].u = *(const uint4*)(Wb + ((size_t)(((nt << 2) + k0) * 64 + lane) << 3));
#pragma unroll
        for (int k0 = 0; k0 < 4; ++k0)
            acc[nt] = __builtin_amdgcn_mfma_f32_16x16x32_bf16(Af[k0].v, Bf[k0].v, acc[nt], 0, 0, 0);
    }

    // fused AS/AD; C/D layout col=lane&15, row=q*4+reg (orig col order)
    float ps[4] = {0.f, 0.f, 0.f, 0.f}, pd[4] = {0.f, 0.f, 0.f, 0.f};
#pragma unroll
    for (int nt = 0; nt < 8; ++nt) {
        float av = asrc[nt * 16 + c];
        float dv = adst[nt * 16 + c];
#pragma unroll
        for (int r = 0; r < 4; ++r) {
            ps[r] = fmaf(acc[nt][r], av, ps[r]);
            pd[r] = fmaf(acc[nt][r], dv, pd[r]);
        }
    }
#pragma unroll
    for (int m = 1; m < 16; m <<= 1) {
#pragma unroll
        for (int r = 0; r < 4; ++r) { ps[r] += __shfl_xor(ps[r], m); pd[r] += __shfl_xor(pd[r], m); }
    }
    if (c == 0) {
#pragma unroll
        for (int r = 0; r < 4; ++r) {
            int grow = r0 + q * 4 + r;
            if (grow < NN) { AS[grow] = ps[r]; AD[grow] = pd[r]; }
        }
    }

    // direct permuted Hb store: lane writes its 8 nt-values as one uint4 per row
#pragma unroll
    for (int r = 0; r < 4; ++r) {
        int grow = r0 + q * 4 + r;
        if (grow < NN) {
            uint4 o;
            o.x = pk2(acc[0][r], acc[1][r]);
            o.y = pk2(acc[2][r], acc[3][r]);
            o.z = pk2(acc[4][r], acc[5][r]);
            o.w = pk2(acc[6][r], acc[7][r]);
            *(uint4*)(Hb + ((size_t)grow << 7) + (c << 3)) = o;
        }
    }
}

// ======================= per-dst softmax + aggregation (single pass) =======================
// Independent waves, NO __syncthreads (r8 post-mortem: block-coupling the skewed-degree
// waves dropped gather BW 45%->34%). Body = measured-best (70us plateau).
template<int OUTBF>
__global__ __launch_bounds__(256) void k_agg(
    const int* __restrict__ off, const int* __restrict__ srcs,
    const unsigned short* __restrict__ Hb, const float* __restrict__ AS,
    const float* __restrict__ AD, const float* __restrict__ bias,
    void* __restrict__ OUT)
{
    __shared__ uint2 s_e[4][64];
    const int wid  = threadIdx.x >> 6;
    const int lane = threadIdx.x & 63;
    const int g    = lane >> 4;     // edge subgroup 0..3
    const int x16  = lane & 15;     // 16-lane column group
    const int n    = blockIdx.x * 4 + wid;
    const int beg = off[n], end = off[n + 1];
    const float adn = AD[n];

    float acc[8];
#pragma unroll
    for (int i = 0; i < 8; ++i) acc[i] = 0.f;
    float den = 0.f;

    for (int base = beg; base < end; base += 64) {
        int cnt = end - base; if (cnt > 64) cnt = 64;
        float wgt = 0.f; int s = 0;
        if (lane < cnt) {
            s = srcs[base + lane];
            float e = AS[s] + adn;
            e = (e > 0.f) ? e : 0.2f * e;
            wgt = __expf(e);
        }
        s_e[wid][lane] = make_uint2((unsigned int)s, __builtin_bit_cast(unsigned int, wgt));
        den += wgt;
        int rounds = (cnt + 3) >> 2;
        for (int j = 0; j < rounds; ++j) {
            uint2 ew = s_e[wid][(j << 2) + g];
            float wq = __builtin_bit_cast(float, ew.y);
            uint4 u = *((const uint4*)(Hb + ((size_t)ew.x << 7)) + x16);
            acc[0] = fmaf(wq, bflo(u.x), acc[0]);
            acc[1] = fmaf(wq, bfhi(u.x), acc[1]);
            acc[2] = fmaf(wq, bflo(u.y), acc[2]);
            acc[3] = fmaf(wq, bfhi(u.y), acc[3]);
            acc[4] = fmaf(wq, bflo(u.z), acc[4]);
            acc[5] = fmaf(wq, bfhi(u.z), acc[5]);
            acc[6] = fmaf(wq, bflo(u.w), acc[6]);
            acc[7] = fmaf(wq, bfhi(u.w), acc[7]);
        }
    }

#pragma unroll
    for (int i = 0; i < 8; ++i) {
        acc[i] += __shfl_xor(acc[i], 16);
        acc[i] += __shfl_xor(acc[i], 32);
    }
#pragma unroll
    for (int o = 32; o; o >>= 1) den += __shfl_xor(den, o);
    float inv = 1.f / den;

    if (g == 0) {
        // acc[i] corresponds to orig col i*16+x16; stored col j = x16*8+i
        float o8[8];
#pragma unroll
        for (int i = 0; i < 8; ++i)
            o8[i] = fmaf(acc[i], inv, bias[i * 16 + x16]);
        if (OUTBF) {
            uint4 pkd;
            pkd.x = pk2(o8[0], o8[1]); pkd.y = pk2(o8[2], o8[3]);
            pkd.z = pk2(o8[4], o8[5]); pkd.w = pk2(o8[6], o8[7]);
            *(uint4*)((unsigned short*)OUT + ((size_t)n << 7) + (x16 << 3)) = pkd;
        } else {
            float* op = (float*)OUT + ((size_t)n << 7) + x16;
#pragma unroll
            for (int i = 0; i < 8; ++i)
                op[i * 16] = o8[i];    // 16 lanes x fixed i = 64B coalesced line
        }
    }
}

// ======================= batchnorm stats from bf16 rows (permuted order — consistent) ======
// r5 lesson: 4 accumulators/thread + dword loads (16-acc/uint4 version spilled to scratch).
__global__ __launch_bounds__(256) void k_colsum(const unsigned int* __restrict__ Xb,
                                                float* __restrict__ gsum, float* __restrict__ gsq) {
    __shared__ float ls[4][128], lq[4][128];
    const int t = threadIdx.x;
    const int c2 = t & 63;      // u32 column index (stored bf16 cols 2*c2, 2*c2+1)
    const int half = t >> 6;    // 4 rows in parallel per block
    float s0 = 0.f, s1 = 0.f, q0 = 0.f, q1 = 0.f;
    for (int r = blockIdx.x * 4 + half; r < NN; r += STAT_BLOCKS * 4) {
        unsigned int v = Xb[(size_t)r * 64 + c2];
        float f0 = bflo(v), f1 = bfhi(v);
        s0 += f0; q0 += f0 * f0;
        s1 += f1; q1 += f1 * f1;
    }
    ls[half][2 * c2] = s0; ls[half][2 * c2 + 1] = s1;
    lq[half][2 * c2] = q0; lq[half][2 * c2 + 1] = q1;
    __syncthreads();
    if (t < 128) {
        float ss = ls[0][t] + ls[1][t] + ls[2][t] + ls[3][t];
        float qq = lq[0][t] + lq[1][t] + lq[2][t] + lq[3][t];
        atomicAdd(&gsum[t], ss);
        atomicAdd(&gsq[t], qq);
    }
}

extern "C" void kernel_launch(void* const* d_in, const int* in_sizes, int n_in,
                              void* d_out, int out_size, void* d_ws, size_t ws_size,
                              hipStream_t stream)
{
    const float* x  = (const float*)d_in[0];
    const int*   ei = (const int*)d_in[1];
    const float* Wm[3]  = {(const float*)d_in[2], (const float*)d_in[6],  (const float*)d_in[10]};
    const float* Asr[3] = {(const float*)d_in[3], (const float*)d_in[7],  (const float*)d_in[11]};
    const float* Ads[3] = {(const float*)d_in[4], (const float*)d_in[8],  (const float*)d_in[12]};
    const float* Bs[3]  = {(const float*)d_in[5], (const float*)d_in[9],  (const float*)d_in[13]};
    const float* gam[2] = {(const float*)d_in[14], (const float*)d_in[16]};
    const float* bet[2] = {(const float*)d_in[15], (const float*)d_in[17]};

    char* p = (char*)d_ws;
    auto carve = [&](size_t bytes) -> char* {
        char* r = p;
        p += (bytes + 255) & ~(size_t)255;
        return r;
    };
    int*   off_   = (int*)carve((size_t)(NN + 1) * 4);
    int*   srcs   = (int*)carve((size_t)ET * 4);
    unsigned int* bucketed = (unsigned int*)carve((size_t)ET * 4);
    int*   btot   = (int*)carve(256 * 4);          // 1024 B, then immediately...
    float* gstat  = (float*)carve(4 * 128 * 4);    // gsum0,gsq0,gsum1,gsq1 — one memset
    int*   bstart = (int*)carve(260 * 4);
    int*   bcur   = (int*)carve(256 * 4);
    unsigned short* Hb  = (unsigned short*)carve((size_t)NP * 128 * 2);
    unsigned short* Wb  = (unsigned short*)carve((size_t)3 * 16384 * 2);  // fragment-major
    float* AS    = (float*)carve((size_t)NN * 4);
    float* AD    = (float*)carve((size_t)NN * 4);

    float*          OUTf = (float*)d_out;            // final fp32 output
    unsigned short* OUTb = (unsigned short*)d_out;   // bf16 intermediate aliases lower half

    // zero btot + both layers' stats in one shot (adjacent carves)
    (void)hipMemsetAsync(btot, 0, 256 * 4 + 4 * 128 * 4, stream);

    // CSR build (bucket sort) + weight cvt fused into the first kernel
    k_pre<<<448, 256, 0, stream>>>(ei, Wm[0], Wm[1], Wm[2], Wb, btot);
    k_bscan<<<1, 256, 0, stream>>>(btot, bstart, bcur, off_);
    k_bucket<<<(ET + TILE - 1) / TILE, 256, 0, stream>>>(ei, bcur, bucketed);
    k_csr<<<NBKT, 256, 0, stream>>>(bucketed, bstart, off_, srcs);

    const int MFMA_GRID = NP / 64;

    // layer 0
    k_mfma<0><<<MFMA_GRID, 256, 0, stream>>>(x, Wb, nullptr, nullptr, nullptr, nullptr,
                                             Asr[0], Ads[0], Hb, AS, AD);
    k_agg<1><<<NN / 4, 256, 0, stream>>>(off_, srcs, Hb, AS, AD, Bs[0], OUTb);
    k_colsum<<<STAT_BLOCKS, 256, 0, stream>>>((const unsigned int*)OUTb, gstat, gstat + 128);

    // layer 1 (BN affine from raw permuted stats; permuted bf16 input)
    k_mfma<1><<<MFMA_GRID, 256, 0, stream>>>(OUTb, Wb + 16384, gstat, gstat + 128,
                                             gam[0], bet[0], Asr[1], Ads[1], Hb, AS, AD);
    k_agg<1><<<NN / 4, 256, 0, stream>>>(off_, srcs, Hb, AS, AD, Bs[1], OUTb);
    k_colsum<<<STAT_BLOCKS, 256, 0, stream>>>((const unsigned int*)OUTb, gstat + 256, gstat + 384);

    // layer 2 (final fp32 output into d_out, unpermuted on write)
    k_mfma<1><<<MFMA_GRID, 256, 0, stream>>>(OUTb, Wb + 32768, gstat + 256, gstat + 384,
                                             gam[1], bet[1], Asr[2], Ads[2], Hb, AS, AD);
    k_agg<0><<<NN / 4, 256, 0, stream>>>(off_, srcs, Hb, AS, AD, Bs[2], OUTf);
}

// Round 10
// 487.129 us; speedup vs baseline: 1.0037x; 1.0037x over previous
//
#include <hip/hip_runtime.h>
#include <cstdint>
#include <cstddef>

#define NN 100000
#define NP 100096          // rows padded to multiple of 64
#define EE 1600000
#define ET 1700000         // EE + NN self-loops
#define NBKT 196           // ceil(NN/512) dst-range buckets
#define TILE 2048          // edges per k_bucket block
#define STAT_BLOCKS 400

typedef short  bf16x8 __attribute__((ext_vector_type(8)));
typedef float  f32x4  __attribute__((ext_vector_type(4)));

__device__ __forceinline__ unsigned short f2bf(float f) {
    unsigned int x = __builtin_bit_cast(unsigned int, f);
    x += 0x7FFFu + ((x >> 16) & 1u);   // RNE
    return (unsigned short)(x >> 16);
}
__device__ __forceinline__ unsigned int pk2(float lo, float hi) {
    return ((unsigned int)f2bf(hi) << 16) | (unsigned int)f2bf(lo);
}
__device__ __forceinline__ float bflo(unsigned int u) {
    return __builtin_bit_cast(float, u << 16);
}
__device__ __forceinline__ float bfhi(unsigned int u) {
    return __builtin_bit_cast(float, u & 0xFFFF0000u);
}
// permuted H layout: stored pos j <-> orig col unperm(j) = ((j&7)<<4)|(j>>3)
// inverse: perm(c) = ((c&15)<<3)|(c>>4)
__device__ __forceinline__ int unperm(int j) { return ((j & 7) << 4) | (j >> 3); }
__device__ __forceinline__ int permf(int c)  { return ((c & 15) << 3) | (c >> 4); }

// ============ fused bcount + weight cvt + attention-vector matvecs (one launch) ============
// blocks 0..255: dst-bucket histogram. blocks 256..447: weight cvt into FRAGMENT-MAJOR
// WbT[(nt*4+k0)*64+lane] (r8: lane-coalesced B-loads, big mfma win). block 448: 6 matvecs
// asv[l][vec][:] = W_l^T a (permuted-space for l>=1) — lets k_mfma compute AS/AD as
// A.(W^T a) during A-prep instead of a 32-shuffle post-MFMA reduce.
__global__ void k_pre(const int* __restrict__ ei,
                      const float* __restrict__ W0, const float* __restrict__ W1,
                      const float* __restrict__ W2,
                      const float* __restrict__ as0, const float* __restrict__ ad0,
                      const float* __restrict__ as1, const float* __restrict__ ad1,
                      const float* __restrict__ as2, const float* __restrict__ ad2,
                      unsigned short* __restrict__ Wb, int* __restrict__ btot,
                      float* __restrict__ asv)
{
    const int t = threadIdx.x;
    const int b = blockIdx.x;
    if (b < 256) {
        __shared__ int h[256];
        h[t] = 0;
        __syncthreads();
        for (int e = b * 256 + t; e < ET; e += 256 * 256) {
            int d = (e < EE) ? ei[EE + e] : (e - EE);
            atomicAdd(&h[d >> 9], 1);
        }
        __syncthreads();
        if (h[t]) atomicAdd(&btot[t], h[t]);
    } else if (b < 448) {
        int i = (b - 256) * 256 + t;       // 0..49151
        int layer = i >> 14;
        const float* W = (layer == 0) ? W0 : (layer == 1) ? W1 : W2;
        int o  = i & 16383;
        int f  = o >> 3, e = o & 7;
        int nt = f >> 8, k0 = (f >> 6) & 3, lane = f & 63;
        int c  = lane & 15, q = lane >> 4;
        int k  = k0 * 32 + q * 8 + e;          // logical k index of A-fragment elem
        int col = (layer == 0) ? k : unperm(k); // layers 1/2 consume permuted H
        Wb[i] = f2bf(W[(nt * 16 + c) * 128 + col]);
    } else {
        // 6 matvecs: thread (vec=t>>7, col=t&127); coalesced W-row loads, broadcast a[n]
        const float* Wl[3] = {W0, W1, W2};
        const float* Al[6] = {as0, ad0, as1, ad1, as2, ad2};
        int vec = t >> 7, col = t & 127;
        for (int l = 0; l < 3; ++l) {
            const float* W = Wl[l];
            const float* a = Al[2 * l + vec];
            float s = 0.f;
            for (int n = 0; n < 128; ++n) s += W[n * 128 + col] * a[n];
            int dc = (l == 0) ? col : permf(col);   // match A's permuted storage
            asv[l * 256 + vec * 128 + dc] = s;
        }
    }
}

// ======================= bucket scatter (btot scan done in-block; k_bscan removed) =========
__global__ __launch_bounds__(256) void k_bucket(
    const int* __restrict__ ei, const int* __restrict__ btot,
    int* __restrict__ bcur0, unsigned int* __restrict__ bucketed)
{
    __shared__ int h4[4][256], woff[4][256], loff[256], gbase[256], sc[256], bst[256];
    __shared__ unsigned int stage[TILE];
    __shared__ int gaddr[TILE];
    __shared__ int stot_s;
    const int t = threadIdx.x;
    const int w = t >> 6;
    const int e0 = blockIdx.x * TILE;

    // exclusive scan of btot (redundant per block, ~free) -> bucket starts
    const int v0 = btot[t];
    bst[t] = v0;
    h4[0][t] = 0; h4[1][t] = 0; h4[2][t] = 0; h4[3][t] = 0;
    __syncthreads();
    for (int o = 1; o < 256; o <<= 1) {
        int a = (t >= o) ? bst[t - o] : 0;
        __syncthreads();
        bst[t] += a;
        __syncthreads();
    }
    const int bstart_t = bst[t] - v0;

    unsigned int pk[TILE / 256];
    int bk[TILE / 256];
#pragma unroll
    for (int i = 0; i < TILE / 256; ++i) {
        int e = e0 + i * 256 + t;
        bk[i] = -1;
        if (e < ET) {
            int s, d;
            if (e < EE) { s = ei[e]; d = ei[EE + e]; } else { s = e - EE; d = s; }
            bk[i] = d >> 9;
            pk[i] = ((unsigned int)(d & 511) << 17) | (unsigned int)s;
            atomicAdd(&h4[w][bk[i]], 1);
        }
    }
    __syncthreads();

    int h0 = h4[0][t], h1 = h4[1][t], h2 = h4[2][t], h3 = h4[3][t];
    int tot = h0 + h1 + h2 + h3;
    sc[t] = tot;
    __syncthreads();
    for (int o = 1; o < 256; o <<= 1) {
        int a = (t >= o) ? sc[t - o] : 0;
        __syncthreads();
        sc[t] += a;
        __syncthreads();
    }
    int lo = sc[t] - tot;
    loff[t] = lo;
    woff[0][t] = lo;
    woff[1][t] = lo + h0;
    woff[2][t] = lo + h0 + h1;
    woff[3][t] = lo + h0 + h1 + h2;
    if (t < NBKT && tot) gbase[t] = bstart_t + atomicAdd(&bcur0[t], tot);
    if (t == 255) stot_s = sc[255];
    h4[0][t] = 0; h4[1][t] = 0; h4[2][t] = 0; h4[3][t] = 0;
    __syncthreads();

#pragma unroll
    for (int i = 0; i < TILE / 256; ++i) {
        if (bk[i] >= 0) {
            int b = bk[i];
            int r = woff[w][b] + atomicAdd(&h4[w][b], 1);
            stage[r] = pk[i];
            gaddr[r] = gbase[b] + (r - loff[b]);
        }
    }
    __syncthreads();

    const int stot = stot_s;
    for (int j = t; j < stot; j += 256)
        bucketed[gaddr[j]] = stage[j];
}

__global__ __launch_bounds__(256) void k_csr(
    const unsigned int* __restrict__ bucketed, const int* __restrict__ btot,
    int* __restrict__ off, int* __restrict__ srcs)
{
    __shared__ int h[512], sc2[512], c2[512], sp[256], bst[256];
    __shared__ int s_beg, s_end;
    const int t = threadIdx.x;
    const int b = blockIdx.x;

    // per-block btot scan -> this bucket's [beg,end)
    const int v0 = btot[t];
    bst[t] = v0;
    __syncthreads();
    for (int o = 1; o < 256; o <<= 1) {
        int a = (t >= o) ? bst[t - o] : 0;
        __syncthreads();
        bst[t] += a;
        __syncthreads();
    }
    if (t == b) { s_end = bst[b]; s_beg = bst[b] - v0; }
    if (b == 0 && t == 0) off[NN] = ET;
    h[t] = 0; h[t + 256] = 0; c2[t] = 0; c2[t + 256] = 0;
    __syncthreads();
    const int beg = s_beg, end = s_end;
    const int cnt = end - beg;

    for (int i = t; i < cnt; i += 256)
        atomicAdd(&h[bucketed[beg + i] >> 17], 1);
    __syncthreads();

    int a0 = h[2 * t], a1 = h[2 * t + 1];
    sp[t] = a0 + a1;
    __syncthreads();
    for (int o = 1; o < 256; o <<= 1) {
        int a = (t >= o) ? sp[t - o] : 0;
        __syncthreads();
        sp[t] += a;
        __syncthreads();
    }
    int ep = sp[t] - (a0 + a1);
    sc2[2 * t] = ep;
    sc2[2 * t + 1] = ep + a0;
    __syncthreads();

    const int d0 = b << 9;
#pragma unroll
    for (int k = t; k < 512; k += 256) {
        int d = d0 + k;
        if (d < NN) off[d] = beg + sc2[k];
    }

    for (int i = t; i < cnt; i += 256) {
        unsigned int v = bucketed[beg + i];
        int ld = v >> 17;
        int r = atomicAdd(&c2[ld], 1);
        srcs[beg + sc2[ld] + r] = (int)(v & 0x1FFFFu);
    }
}

// ======================= MFMA GEMM: H = X @ W^T, fused BN-affine/relu/cvt + AS/AD ===========
// MODE 0: fp32 X (layer 0); MODE 1: permuted-bf16 X + BN affine + relu.
// r10: AS/AD via A.(W^T a) folded into A-prep (ws/wd in LDS) — replaces the post-MFMA
// 32-shuffle reduce with 16 ds_read_b128 + 4 shuffles, and decouples AS/AD from MFMA.
template<int MODE>
__global__ __launch_bounds__(256) void k_mfma(
    const void* __restrict__ Xv, const unsigned short* __restrict__ Wb,
    const float* __restrict__ gsum, const float* __restrict__ gsq,
    const float* __restrict__ gamma, const float* __restrict__ beta,
    const float* __restrict__ wsd,       // 256 floats: ws[128], wd[128] (A-storage order)
    unsigned short* __restrict__ Hb, float* __restrict__ AS, float* __restrict__ AD)
{
    __shared__ float ws_s[128], wd_s[128], scale_s[128], shift_s[128];
    const int t    = threadIdx.x;
    const int lane = t & 63;
    const int c    = lane & 15;
    const int q    = lane >> 4;
    const int r0   = blockIdx.x * 64 + (t >> 6) * 16;
    const int row  = r0 + c;

    if (t < 128) {
        ws_s[t] = wsd[t];
        wd_s[t] = wsd[128 + t];
        if (MODE) {
            // BN affine from raw sums; stats arrive in PERMUTED/stored col order
            int ot = unperm(t);
            float mu  = gsum[t] * (1.f / NN);
            float var = gsq[t] * (1.f / NN) - mu * mu;
            float sc  = gamma[ot] * rsqrtf(var + 1e-5f);
            scale_s[t] = sc;
            shift_s[t] = beta[ot] - mu * sc;
        }
    }
    __syncthreads();

    union { uint4 u; bf16x8 v; } Af[4];
    float asp = 0.f, adp = 0.f;
    if (row < NN) {
        if (MODE) {
            const unsigned short* xp = (const unsigned short*)Xv + ((size_t)row << 7) + (q << 3);
#pragma unroll
            for (int k0 = 0; k0 < 4; ++k0) {
                uint4 r = *(const uint4*)(xp + (k0 << 5));
                const int kb = (k0 << 5) + (q << 3);
                float a0 = bflo(r.x), a1 = bfhi(r.x), a2 = bflo(r.y), a3 = bfhi(r.y);
                float a4 = bflo(r.z), a5 = bfhi(r.z), a6 = bflo(r.w), a7 = bfhi(r.w);
                float4 sA = *(const float4*)&scale_s[kb];
                float4 sB = *(const float4*)&scale_s[kb + 4];
                float4 hA = *(const float4*)&shift_s[kb];
                float4 hB = *(const float4*)&shift_s[kb + 4];
                a0 = fmaxf(0.f, fmaf(a0, sA.x, hA.x));
                a1 = fmaxf(0.f, fmaf(a1, sA.y, hA.y));
                a2 = fmaxf(0.f, fmaf(a2, sA.z, hA.z));
                a3 = fmaxf(0.f, fmaf(a3, sA.w, hA.w));
                a4 = fmaxf(0.f, fmaf(a4, sB.x, hB.x));
                a5 = fmaxf(0.f, fmaf(a5, sB.y, hB.y));
                a6 = fmaxf(0.f, fmaf(a6, sB.z, hB.z));
                a7 = fmaxf(0.f, fmaf(a7, sB.w, hB.w));
                float4 wa = *(const float4*)&ws_s[kb];
                float4 wb = *(const float4*)&ws_s[kb + 4];
                float4 da = *(const float4*)&wd_s[kb];
                float4 db = *(const float4*)&wd_s[kb + 4];
                asp = fmaf(a0, wa.x, fmaf(a1, wa.y, fmaf(a2, wa.z, fmaf(a3, wa.w, asp))));
                asp = fmaf(a4, wb.x, fmaf(a5, wb.y, fmaf(a6, wb.z, fmaf(a7, wb.w, asp))));
                adp = fmaf(a0, da.x, fmaf(a1, da.y, fmaf(a2, da.z, fmaf(a3, da.w, adp))));
                adp = fmaf(a4, db.x, fmaf(a5, db.y, fmaf(a6, db.z, fmaf(a7, db.w, adp))));
                Af[k0].u.x = pk2(a0, a1);
                Af[k0].u.y = pk2(a2, a3);
                Af[k0].u.z = pk2(a4, a5);
                Af[k0].u.w = pk2(a6, a7);
            }
        } else {
            const float* xp = (const float*)Xv + ((size_t)row << 7) + (q << 3);
#pragma unroll
            for (int k0 = 0; k0 < 4; ++k0) {
                float4 a = *(const float4*)(xp + (k0 << 5));
                float4 b = *(const float4*)(xp + (k0 << 5) + 4);
                const int kb = (k0 << 5) + (q << 3);
                float4 wa = *(const float4*)&ws_s[kb];
                float4 wb = *(const float4*)&ws_s[kb + 4];
                float4 da = *(const float4*)&wd_s[kb];
                float4 db = *(const float4*)&wd_s[kb + 4];
                asp = fmaf(a.x, wa.x, fmaf(a.y, wa.y, fmaf(a.z, wa.z, fmaf(a.w, wa.w, asp))));
                asp = fmaf(b.x, wb.x, fmaf(b.y, wb.y, fmaf(b.z, wb.z, fmaf(b.w, wb.w, asp))));
                adp = fmaf(a.x, da.x, fmaf(a.y, da.y, fmaf(a.z, da.z, fmaf(a.w, da.w, adp))));
                adp = fmaf(b.x, db.x, fmaf(b.y, db.y, fmaf(b.z, db.z, fmaf(b.w, db.w, adp))));
                Af[k0].u.x = pk2(a.x, a.y);
                Af[k0].u.y = pk2(a.z, a.w);
                Af[k0].u.z = pk2(b.x, b.y);
                Af[k0].u.w = pk2(b.z, b.w);
            }
        }
    } else {
#pragma unroll
        for (int k0 = 0; k0 < 4; ++k0) Af[k0].u = make_uint4(0, 0, 0, 0);
    }

    // AS/AD finish: reduce over the 4 q-lanes of each row (independent of MFMA)
    asp += __shfl_xor(asp, 16); asp += __shfl_xor(asp, 32);
    adp += __shfl_xor(adp, 16); adp += __shfl_xor(adp, 32);
    if (lane < 16) {
        int grow = r0 + lane;
        if (grow < NN) { AS[grow] = asp; AD[grow] = adp; }
    }

    f32x4 acc[8];
#pragma unroll
    for (int nt = 0; nt < 8; ++nt) acc[nt] = (f32x4){0.f, 0.f, 0.f, 0.f};

#pragma unroll
    for (int nt = 0; nt < 8; ++nt) {
        union { uint4 u; bf16x8 v; } Bf[4];
#pragma unroll
        for (int k0 = 0; k0 < 4; ++k0)
            Bf[k0].u = *(const uint4*)(Wb + ((size_t)(((nt << 2) + k0) * 64 + lane) << 3));
#pragma unroll
        for (int k0 = 0; k0 < 4; ++k0)
            acc[nt] = __builtin_amdgcn_mfma_f32_16x16x32_bf16(Af[k0].v, Bf[k0].v, acc[nt], 0, 0, 0);
    }

    // direct permuted Hb store (r6): lane writes its 8 nt-values as one uint4 per row
#pragma unroll
    for (int r = 0; r < 4; ++r) {
        int grow = r0 + q * 4 + r;
        if (grow < NN) {
            uint4 o;
            o.x = pk2(acc[0][r], acc[1][r]);
            o.y = pk2(acc[2][r], acc[3][r]);
            o.z = pk2(acc[4][r], acc[5][r]);
            o.w = pk2(acc[6][r], acc[7][r]);
            *(uint4*)(Hb + ((size_t)grow << 7) + (c << 3)) = o;
        }
    }
}

// ======================= per-dst softmax + aggregation (single pass) =======================
// FROZEN at the measured-best structure (71us plateau over 6 variants). Independent waves,
// no __syncthreads (r8: block-coupling skewed-degree waves dropped gather BW 45%->34%).
template<int OUTBF>
__global__ __launch_bounds__(256) void k_agg(
    const int* __restrict__ off, const int* __restrict__ srcs,
    const unsigned short* __restrict__ Hb, const float* __restrict__ AS,
    const float* __restrict__ AD, const float* __restrict__ bias,
    void* __restrict__ OUT)
{
    __shared__ uint2 s_e[4][64];
    const int wid  = threadIdx.x >> 6;
    const int lane = threadIdx.x & 63;
    const int g    = lane >> 4;     // edge subgroup 0..3
    const int x16  = lane & 15;     // 16-lane column group
    const int n    = blockIdx.x * 4 + wid;
    const int beg = off[n], end = off[n + 1];
    const float adn = AD[n];

    float acc[8];
#pragma unroll
    for (int i = 0; i < 8; ++i) acc[i] = 0.f;
    float den = 0.f;

    for (int base = beg; base < end; base += 64) {
        int cnt = end - base; if (cnt > 64) cnt = 64;
        float wgt = 0.f; int s = 0;
        if (lane < cnt) {
            s = srcs[base + lane];
            float e = AS[s] + adn;
            e = (e > 0.f) ? e : 0.2f * e;
            wgt = __expf(e);
        }
        s_e[wid][lane] = make_uint2((unsigned int)s, __builtin_bit_cast(unsigned int, wgt));
        den += wgt;
        int rounds = (cnt + 3) >> 2;
        for (int j = 0; j < rounds; ++j) {
            uint2 ew = s_e[wid][(j << 2) + g];
            float wq = __builtin_bit_cast(float, ew.y);
            uint4 u = *((const uint4*)(Hb + ((size_t)ew.x << 7)) + x16);
            acc[0] = fmaf(wq, bflo(u.x), acc[0]);
            acc[1] = fmaf(wq, bfhi(u.x), acc[1]);
            acc[2] = fmaf(wq, bflo(u.y), acc[2]);
            acc[3] = fmaf(wq, bfhi(u.y), acc[3]);
            acc[4] = fmaf(wq, bflo(u.z), acc[4]);
            acc[5] = fmaf(wq, bfhi(u.z), acc[5]);
            acc[6] = fmaf(wq, bflo(u.w), acc[6]);
            acc[7] = fmaf(wq, bfhi(u.w), acc[7]);
        }
    }

#pragma unroll
    for (int i = 0; i < 8; ++i) {
        acc[i] += __shfl_xor(acc[i], 16);
        acc[i] += __shfl_xor(acc[i], 32);
    }
#pragma unroll
    for (int o = 32; o; o >>= 1) den += __shfl_xor(den, o);
    float inv = 1.f / den;

    if (g == 0) {
        // acc[i] corresponds to orig col i*16+x16; stored col j = x16*8+i
        float o8[8];
#pragma unroll
        for (int i = 0; i < 8; ++i)
            o8[i] = fmaf(acc[i], inv, bias[i * 16 + x16]);
        if (OUTBF) {
            uint4 pkd;
            pkd.x = pk2(o8[0], o8[1]); pkd.y = pk2(o8[2], o8[3]);
            pkd.z = pk2(o8[4], o8[5]); pkd.w = pk2(o8[6], o8[7]);
            *(uint4*)((unsigned short*)OUT + ((size_t)n << 7) + (x16 << 3)) = pkd;
        } else {
            float* op = (float*)OUT + ((size_t)n << 7) + x16;
#pragma unroll
            for (int i = 0; i < 8; ++i)
                op[i * 16] = o8[i];    // 16 lanes x fixed i = 64B coalesced line
        }
    }
}

// ======================= batchnorm stats from bf16 rows (permuted order — consistent) ======
// r5 lesson: 4 accumulators/thread + dword loads (16-acc/uint4 version spilled to scratch).
__global__ __launch_bounds__(256) void k_colsum(const unsigned int* __restrict__ Xb,
                                                float* __restrict__ gsum, float* __restrict__ gsq) {
    __shared__ float ls[4][128], lq[4][128];
    const int t = threadIdx.x;
    const int c2 = t & 63;      // u32 column index (stored bf16 cols 2*c2, 2*c2+1)
    const int half = t >> 6;    // 4 rows in parallel per block
    float s0 = 0.f, s1 = 0.f, q0 = 0.f, q1 = 0.f;
    for (int r = blockIdx.x * 4 + half; r < NN; r += STAT_BLOCKS * 4) {
        unsigned int v = Xb[(size_t)r * 64 + c2];
        float f0 = bflo(v), f1 = bfhi(v);
        s0 += f0; q0 += f0 * f0;
        s1 += f1; q1 += f1 * f1;
    }
    ls[half][2 * c2] = s0; ls[half][2 * c2 + 1] = s1;
    lq[half][2 * c2] = q0; lq[half][2 * c2 + 1] = q1;
    __syncthreads();
    if (t < 128) {
        float ss = ls[0][t] + ls[1][t] + ls[2][t] + ls[3][t];
        float qq = lq[0][t] + lq[1][t] + lq[2][t] + lq[3][t];
        atomicAdd(&gsum[t], ss);
        atomicAdd(&gsq[t], qq);
    }
}

extern "C" void kernel_launch(void* const* d_in, const int* in_sizes, int n_in,
                              void* d_out, int out_size, void* d_ws, size_t ws_size,
                              hipStream_t stream)
{
    const float* x  = (const float*)d_in[0];
    const int*   ei = (const int*)d_in[1];
    const float* Wm[3]  = {(const float*)d_in[2], (const float*)d_in[6],  (const float*)d_in[10]};
    const float* Asr[3] = {(const float*)d_in[3], (const float*)d_in[7],  (const float*)d_in[11]};
    const float* Ads[3] = {(const float*)d_in[4], (const float*)d_in[8],  (const float*)d_in[12]};
    const float* Bs[3]  = {(const float*)d_in[5], (const float*)d_in[9],  (const float*)d_in[13]};
    const float* gam[2] = {(const float*)d_in[14], (const float*)d_in[16]};
    const float* bet[2] = {(const float*)d_in[15], (const float*)d_in[17]};

    char* p = (char*)d_ws;
    auto carve = [&](size_t bytes) -> char* {
        char* r = p;
        p += (bytes + 255) & ~(size_t)255;
        return r;
    };
    int*   off_   = (int*)carve((size_t)(NN + 1) * 4);
    int*   srcs   = (int*)carve((size_t)ET * 4);
    unsigned int* bucketed = (unsigned int*)carve((size_t)ET * 4);
    int*   btot   = (int*)carve(256 * 4);          // adjacent: one memset covers all three
    int*   bcur0  = (int*)carve(256 * 4);
    float* gstat  = (float*)carve(4 * 128 * 4);    // gsum0,gsq0,gsum1,gsq1
    float* asv    = (float*)carve(3 * 256 * 4);    // per-layer [ws|wd] vectors
    unsigned short* Hb  = (unsigned short*)carve((size_t)NP * 128 * 2);
    unsigned short* Wb  = (unsigned short*)carve((size_t)3 * 16384 * 2);  // fragment-major
    float* AS    = (float*)carve((size_t)NN * 4);
    float* AD    = (float*)carve((size_t)NN * 4);

    float*          OUTf = (float*)d_out;            // final fp32 output
    unsigned short* OUTb = (unsigned short*)d_out;   // bf16 intermediate aliases lower half

    // zero btot + bcur0 + stats in one shot (adjacent carves)
    (void)hipMemsetAsync(btot, 0, 256 * 4 + 256 * 4 + 4 * 128 * 4, stream);

    // build: hist+cvtw+matvecs, then bucket scatter, then per-bucket CSR (bscan folded in)
    k_pre<<<449, 256, 0, stream>>>(ei, Wm[0], Wm[1], Wm[2],
                                   Asr[0], Ads[0], Asr[1], Ads[1], Asr[2], Ads[2],
                                   Wb, btot, asv);
    k_bucket<<<(ET + TILE - 1) / TILE, 256, 0, stream>>>(ei, btot, bcur0, bucketed);
    k_csr<<<NBKT, 256, 0, stream>>>(bucketed, btot, off_, srcs);

    const int MFMA_GRID = NP / 64;

    // layer 0
    k_mfma<0><<<MFMA_GRID, 256, 0, stream>>>(x, Wb, nullptr, nullptr, nullptr, nullptr,
                                             asv, Hb, AS, AD);
    k_agg<1><<<NN / 4, 256, 0, stream>>>(off_, srcs, Hb, AS, AD, Bs[0], OUTb);
    k_colsum<<<STAT_BLOCKS, 256, 0, stream>>>((const unsigned int*)OUTb, gstat, gstat + 128);

    // layer 1
    k_mfma<1><<<MFMA_GRID, 256, 0, stream>>>(OUTb, Wb + 16384, gstat, gstat + 128,
                                             gam[0], bet[0], asv + 256, Hb, AS, AD);
    k_agg<1><<<NN / 4, 256, 0, stream>>>(off_, srcs, Hb, AS, AD, Bs[1], OUTb);
    k_colsum<<<STAT_BLOCKS, 256, 0, stream>>>((const unsigned int*)OUTb, gstat + 256, gstat + 384);

    // layer 2 (final fp32 output into d_out, unpermuted on write)
    k_mfma<1><<<MFMA_GRID, 256, 0, stream>>>(OUTb, Wb + 32768, gstat + 256, gstat + 384,
                                             gam[1], bet[1], asv + 512, Hb, AS, AD);
    k_agg<0><<<NN / 4, 256, 0, stream>>>(off_, srcs, Hb, AS, AD, Bs[2], OUTf);
}